// Round 3
// baseline (55.389 us; speedup 1.0000x reference)
//
#include <hip/hip_runtime.h>
#include <math.h>

// Problem constants
#define B_  32
#define D_  64
#define L_  4096
#define E_  8
#define OC_ 32
#define LP_ 4094   // L - 2 (VALID conv, kernel 3)
#define TILE 128
#define NT   32    // tiles per batch (4096/128)

typedef __attribute__((ext_vector_type(8)))  short short8;
typedef __attribute__((ext_vector_type(16))) float float16;

static __device__ __forceinline__ unsigned short f2bf(float f) {
    unsigned u = __float_as_uint(f);
    return (unsigned short)((u + 0x7fffu + ((u >> 16) & 1u)) >> 16);
}

// ---------------------------------------------------------------------------
// Single fused kernel:
//   - per-block (redundant, cheap) gate computation: softmax(g_in @ w_gate),
//     top-2, renormalize -> (i0,g0),(i1,g1)
//   - stage x tile [c][l] -> bf16 transposed LDS xT[l][c] (XOR-swizzled)
//   - conv1 as implicit GEMM: 12 x mfma_32x32x16_bf16 (A=weights built
//     in-register from L2-resident c1w, B=xT)
//   - bias + tanh -> wave-private LDS H
//   - conv2 (1x1) + MoE collapsed to per-batch 32x32 W_eff: 2 x mfma
//   - + bias, store f32
// Block = (batch, 128-col L tile); 4 waves, one 32-col MFMA tile each.
// ---------------------------------------------------------------------------
__global__ __launch_bounds__(256, 4)
void fused_all(const float* __restrict__ x,
               const float* __restrict__ w_gate,  // [320][8]
               const float* __restrict__ c1w,     // [32][64][3]
               const float* __restrict__ c1b,     // [32]
               const float* __restrict__ c2w,     // [256][32]
               const float* __restrict__ c2b,     // [256]
               float* __restrict__ out)           // [B][32][4094]
{
    // xT: [132 rows(l)][64 c] bf16, row pitch 128 B, XOR-swizzle (row&7)<<4
    __shared__ __align__(16) unsigned short xT[132 * 64];
    // H: per-wave [32 col][pitch 40] bf16
    __shared__ __align__(16) unsigned short Hl[4 * 32 * 40];

    const int tid  = threadIdx.x;
    const int lane = tid & 63;
    const int wv   = tid >> 6;
    const int b    = blockIdx.x >> 5;
    const int l0   = (blockIdx.x & 31) << 7;
    const float* xb = x + (size_t)b * (D_ * L_);

    // ---- stage x tile (transpose f32 [c][l] -> bf16 xT[l][c], c-pairs) ----
    {
        const int c2 = tid >> 3;          // 0..31 channel pair
        const int jb = (tid & 7) << 2;    // 0,4,..,28
        const float* p0 = xb + (size_t)(2 * c2) * L_ + l0;
        const float* p1 = p0 + L_;
        #pragma unroll
        for (int jq = 0; jq < 4; ++jq) {
            int j = jq * 32 + jb;
            float4 v0 = *(const float4*)(p0 + j);
            float4 v1 = *(const float4*)(p1 + j);
            float e0[4] = {v0.x, v0.y, v0.z, v0.w};
            float e1[4] = {v1.x, v1.y, v1.z, v1.w};
            #pragma unroll
            for (int r = 0; r < 4; ++r) {
                int row = j + r;
                unsigned pk = (unsigned)f2bf(e0[r]) | ((unsigned)f2bf(e1[r]) << 16);
                int off = (row * 128 + c2 * 4) ^ ((row & 7) << 4);
                *(unsigned*)((char*)xT + off) = pk;
            }
        }
        // halo rows 128,129 (zero past l=4095)
        if (tid < 64) {
            int cc2 = tid >> 1, jj = tid & 1;
            int row = TILE + jj;
            int lg  = l0 + row;
            float f0 = 0.f, f1 = 0.f;
            if (lg < L_) {
                f0 = xb[(size_t)(2 * cc2) * L_ + lg];
                f1 = xb[(size_t)(2 * cc2 + 1) * L_ + lg];
            }
            unsigned pk = (unsigned)f2bf(f0) | ((unsigned)f2bf(f1) << 16);
            int off = (row * 128 + cc2 * 4) ^ ((row & 7) << 4);
            *(unsigned*)((char*)xT + off) = pk;
        }
    }

    // ---- gates (each wave redundantly; lane = channel d) ----
    const int d = lane;
    float xv[5];
    #pragma unroll
    for (int t = 0; t < 5; ++t)
        xv[t] = xb[(size_t)d * L_ + (L_ - 6) + t];

    float wg[40];
    {
        const float* wgp = w_gate + d * 40;
        #pragma unroll
        for (int q = 0; q < 10; ++q)
            *(float4*)(wg + q * 4) = *(const float4*)(wgp + q * 4);
    }
    float part[E_];
    #pragma unroll
    for (int e = 0; e < E_; ++e) part[e] = 0.f;
    #pragma unroll
    for (int t = 0; t < 5; ++t) {
        #pragma unroll
        for (int e = 0; e < E_; ++e) part[e] += xv[t] * wg[t * 8 + e];
    }
    #pragma unroll
    for (int off = 1; off < 64; off <<= 1) {
        #pragma unroll
        for (int e = 0; e < E_; ++e)
            part[e] += __shfl_xor(part[e], off, 64);
    }
    float m = part[0];
    #pragma unroll
    for (int e = 1; e < E_; ++e) m = fmaxf(m, part[e]);
    float p[E_], s = 0.f;
    #pragma unroll
    for (int e = 0; e < E_; ++e) { p[e] = expf(part[e] - m); s += p[e]; }
    float inv = 1.f / s;
    #pragma unroll
    for (int e = 0; e < E_; ++e) p[e] *= inv;

    int i0 = 0;
    #pragma unroll
    for (int e = 1; e < E_; ++e) if (p[e] > p[i0]) i0 = e;
    int i1 = (i0 == 0) ? 1 : 0;
    #pragma unroll
    for (int e = 0; e < E_; ++e) {
        if (e == i0) continue;
        if (p[e] > p[i1]) i1 = e;
    }
    const float v0 = p[i0], v1 = p[i1];
    const float den = v0 + v1 + 1e-6f;
    const float g0 = v0 / den, g1 = v1 / den;

    const int cl = lane & 31;
    const int hi = lane >> 5;

    // conv2 W_eff A-fragments: A[m=dd=cl][k=oc], oc = ks*16 + hi*8 + i
    short8 a2[2];
    #pragma unroll
    for (int ks = 0; ks < 2; ++ks) {
        const float* q0 = c2w + (cl * E_ + i0) * OC_ + ks * 16 + hi * 8;
        const float* q1 = c2w + (cl * E_ + i1) * OC_ + ks * 16 + hi * 8;
        float4 u0a = *(const float4*)q0, u0b = *(const float4*)(q0 + 4);
        float4 u1a = *(const float4*)q1, u1b = *(const float4*)(q1 + 4);
        float v[8] = {
            g0 * u0a.x + g1 * u1a.x, g0 * u0a.y + g1 * u1a.y,
            g0 * u0a.z + g1 * u1a.z, g0 * u0a.w + g1 * u1a.w,
            g0 * u0b.x + g1 * u1b.x, g0 * u0b.y + g1 * u1b.y,
            g0 * u0b.z + g1 * u1b.z, g0 * u0b.w + g1 * u1b.w };
        #pragma unroll
        for (int i = 0; i < 8; ++i) a2[ks][i] = (short)f2bf(v[i]);
    }

    // biases per C/D row: row = (r&3) + 8*(r>>2) + 4*hi
    float bias1[16], bias2[16];
    #pragma unroll
    for (int r = 0; r < 16; ++r) {
        int row = (r & 3) + 8 * (r >> 2) + 4 * hi;
        bias1[r] = c1b[row];
        bias2[r] = g0 * c2b[row * E_ + i0] + g1 * c2b[row * E_ + i1];
    }

    __syncthreads();

    // ---- conv1: 12 x mfma over K' = t*64 + c; A built in-register ----
    const int cb = wv * 32;
    float16 acc = (float16)0.0f;
    #pragma unroll
    for (int t = 0; t < 3; ++t) {
        int row = cb + cl + t;
        int rb  = row * 128;
        int swz = (row & 7) << 4;
        #pragma unroll
        for (int q = 0; q < 4; ++q) {
            // A frag: c = q*16 + hi*8 + i, w = c1w[cl*192 + c*3 + t]
            short8 af;
            const float* wp = c1w + cl * 192 + (q * 16 + hi * 8) * 3 + t;
            #pragma unroll
            for (int i = 0; i < 8; ++i) af[i] = (short)f2bf(wp[3 * i]);
            int off = (rb + q * 32 + hi * 16) ^ swz;
            short8 bf = *(const short8*)((const char*)xT + off);
            acc = __builtin_amdgcn_mfma_f32_32x32x16_bf16(af, bf, acc, 0, 0, 0);
        }
    }

    // ---- bias + tanh -> wave-private LDS H (bf16, row pairs packed) ----
    unsigned short* Hb = Hl + wv * (32 * 40);
    #pragma unroll
    for (int j = 0; j < 8; ++j) {
        int r2  = 2 * j;
        int row = (r2 & 3) + 8 * (r2 >> 2) + 4 * hi;
        float h0 = tanhf(acc[r2]     + bias1[r2]);
        float h1 = tanhf(acc[r2 + 1] + bias1[r2 + 1]);
        unsigned pk = (unsigned)f2bf(h0) | ((unsigned)f2bf(h1) << 16);
        *(unsigned*)&Hb[cl * 40 + row] = pk;
    }

    // ---- conv2: 2 x mfma, B = H[oc][col] ----
    float16 acc2 = (float16)0.0f;
    #pragma unroll
    for (int ks = 0; ks < 2; ++ks) {
        short8 bf = *(const short8*)&Hb[cl * 40 + ks * 16 + hi * 8];
        acc2 = __builtin_amdgcn_mfma_f32_32x32x16_bf16(a2[ks], bf, acc2, 0, 0, 0);
    }

    // ---- store ----
    int l = l0 + cb + cl;
    if (l < LP_) {
        float* ob = out + (size_t)b * (OC_ * (size_t)LP_) + l;
        #pragma unroll
        for (int r = 0; r < 16; ++r) {
            int row = (r & 3) + 8 * (r >> 2) + 4 * hi;
            ob[(size_t)row * LP_] = acc2[r] + bias2[r];
        }
    }
}

// ---------------------------------------------------------------------------
extern "C" void kernel_launch(void* const* d_in, const int* in_sizes, int n_in,
                              void* d_out, int out_size, void* d_ws, size_t ws_size,
                              hipStream_t stream)
{
    const float* x      = (const float*)d_in[0];
    const float* w_gate = (const float*)d_in[1];
    const float* c1w    = (const float*)d_in[2];
    const float* c1b    = (const float*)d_in[3];
    const float* c2w    = (const float*)d_in[4];
    const float* c2b    = (const float*)d_in[5];
    float* out = (float*)d_out;

    fused_all<<<B_ * NT, 256, 0, stream>>>(x, w_gate, c1w, c1b, c2w, c2b, out);
}

// Round 4
// 25.427 us; speedup vs baseline: 2.1783x; 2.1783x over previous
//
#include <hip/hip_runtime.h>
#include <math.h>

// Problem constants
#define B_  32
#define D_  64
#define L_  4096
#define E_  8
#define OC_ 32
#define LP_ 4094   // L - 2 (VALID conv, kernel 3)
#define TILE 128
#define NT   32    // tiles per batch (4096/128)

typedef __attribute__((ext_vector_type(8)))  short short8;
typedef __attribute__((ext_vector_type(16))) float float16;

static __device__ __forceinline__ unsigned short f2bf(float f) {
    unsigned u = __float_as_uint(f);
    return (unsigned short)((u + 0x7fffu + ((u >> 16) & 1u)) >> 16);
}
static __device__ __forceinline__ unsigned pkbf(float a, float b) {
    return (unsigned)f2bf(a) | ((unsigned)f2bf(b) << 16);
}

// ---------------------------------------------------------------------------
// Workspace: beff f32[32][32] @0 (4KB) | aF bf16[12][64][8] @4096 (12KB)
//            wf2 bf16[B][2][64][8] @16384 (64KB)
// ---------------------------------------------------------------------------

// Prep: blocks 0..7 (wave w -> batch 4*blk+w): gates + Weff frags + beff.
//       block 8: conv1 A-fragments (coalesced-consumable layout).
__global__ __launch_bounds__(256)
void prep_kernel(const float* __restrict__ x,
                 const float* __restrict__ w_gate,
                 const float* __restrict__ c1w,
                 const float* __restrict__ c2w,
                 const float* __restrict__ c2b,
                 float* __restrict__ beff,
                 unsigned short* __restrict__ aF,
                 unsigned short* __restrict__ wf2)
{
    const int tid = threadIdx.x;

    if (blockIdx.x == 8) {
        // aF[i], i = ks*512 + lane*8 + ii ; kp = ks*16 + (lane>>5)*8 + ii
        for (int i = tid; i < 12 * 64 * 8; i += 256) {
            int ks = i >> 9, lane = (i >> 3) & 63, ii = i & 7;
            int oc = lane & 31, half = lane >> 5;
            int kp = ks * 16 + half * 8 + ii;
            int t = kp >> 6, c = kp & 63;
            aF[i] = f2bf(c1w[oc * 192 + c * 3 + t]);
        }
        return;
    }

    const int wv = tid >> 6, lane = tid & 63;
    const int b  = blockIdx.x * 4 + wv;
    const int d  = lane;

    float xv[5];
    #pragma unroll
    for (int t = 0; t < 5; ++t)
        xv[t] = x[((size_t)b * D_ + d) * L_ + (L_ - 6) + t];

    float part[E_];
    #pragma unroll
    for (int e = 0; e < E_; ++e) part[e] = 0.f;
    #pragma unroll
    for (int t = 0; t < 5; ++t) {
        const float* wg = w_gate + (d * 5 + t) * E_;
        #pragma unroll
        for (int e = 0; e < E_; ++e) part[e] += xv[t] * wg[e];
    }
    #pragma unroll
    for (int off = 1; off < 64; off <<= 1) {
        #pragma unroll
        for (int e = 0; e < E_; ++e)
            part[e] += __shfl_xor(part[e], off, 64);
    }
    float m = part[0];
    #pragma unroll
    for (int e = 1; e < E_; ++e) m = fmaxf(m, part[e]);
    float p[E_], s = 0.f;
    #pragma unroll
    for (int e = 0; e < E_; ++e) { p[e] = expf(part[e] - m); s += p[e]; }
    float inv = 1.f / s;
    #pragma unroll
    for (int e = 0; e < E_; ++e) p[e] *= inv;

    int i0 = 0;
    #pragma unroll
    for (int e = 1; e < E_; ++e) if (p[e] > p[i0]) i0 = e;
    int i1 = (i0 == 0) ? 1 : 0;
    #pragma unroll
    for (int e = 0; e < E_; ++e) {
        if (e == i0) continue;
        if (p[e] > p[i1]) i1 = e;
    }
    const float v0 = p[i0], v1 = p[i1];
    const float den = v0 + v1 + 1e-6f;
    const float g0 = v0 / den, g1 = v1 / den;

    // Weff A-frags: A[m=dd=cl][k=oc], oc = ks*16 + (lane>>5)*8 + i
    {
        const int dd = lane & 31, half = lane >> 5;
        #pragma unroll
        for (int ks = 0; ks < 2; ++ks) {
            #pragma unroll
            for (int i = 0; i < 8; ++i) {
                int oc = ks * 16 + half * 8 + i;
                float v = g0 * c2w[(dd * E_ + i0) * OC_ + oc]
                        + g1 * c2w[(dd * E_ + i1) * OC_ + oc];
                wf2[((b * 2 + ks) * 64 + lane) * 8 + i] = f2bf(v);
            }
        }
    }
    if (d < OC_)
        beff[b * OC_ + d] = g0 * c2b[d * E_ + i0] + g1 * c2b[d * E_ + i1];
}

// ---------------------------------------------------------------------------
// Fused main. Block = (batch, 128-col tile); 4 waves, one 32-col MFMA tile
// each. conv2 B-operand assembled in-register via half-wave shuffle swap
// (no H LDS bounce); output bounced through LDS for contiguous f32x4 stores.
// ---------------------------------------------------------------------------
__global__ __launch_bounds__(256, 6)
void fused_main(const float* __restrict__ x,
                const unsigned short* __restrict__ aF,   // [12][64][8]
                const unsigned short* __restrict__ wf2,  // [B][2][64][8]
                const float* __restrict__ beff,          // [B][32]
                const float* __restrict__ c1b,           // [32]
                float* __restrict__ out)                 // [B][32][4094]
{
    // union: phase A = xT bf16 [130 rows][64 c] pitch 128B, XOR-swizzled;
    //        phase B = outS f32 [32 rows][pitch 136]
    __shared__ __align__(16) float smem[32 * 136];  // 17408 B
    unsigned short* xT = (unsigned short*)smem;

    const int tid  = threadIdx.x;
    const int lane = tid & 63;
    const int wv   = tid >> 6;
    const int b    = blockIdx.x >> 5;
    const int l0   = (blockIdx.x & 31) << 7;
    const float* xb = x + (size_t)b * (D_ * L_);

    // ---- stage x tile: f32 [c][l] -> bf16 xT[l][c] (c-pairs packed) ----
    {
        const int c2 = tid >> 3;          // 0..31 channel pair
        const int jb = (tid & 7) << 2;
        const float* p0 = xb + (size_t)(2 * c2) * L_ + l0;
        const float* p1 = p0 + L_;
        #pragma unroll
        for (int jq = 0; jq < 4; ++jq) {
            int j = jq * 32 + jb;
            float4 v0 = *(const float4*)(p0 + j);
            float4 v1 = *(const float4*)(p1 + j);
            float e0[4] = {v0.x, v0.y, v0.z, v0.w};
            float e1[4] = {v1.x, v1.y, v1.z, v1.w};
            #pragma unroll
            for (int r = 0; r < 4; ++r) {
                int row = j + r;
                int off = (row * 128 + c2 * 4) ^ ((row & 7) << 4);
                *(unsigned*)((char*)xT + off) = pkbf(e0[r], e1[r]);
            }
        }
        if (tid < 64) {  // halo rows 128,129
            int cc2 = tid >> 1, jj = tid & 1;
            int row = TILE + jj;
            int lg  = l0 + row;
            float f0 = 0.f, f1 = 0.f;
            if (lg < L_) {
                f0 = xb[(size_t)(2 * cc2) * L_ + lg];
                f1 = xb[(size_t)(2 * cc2 + 1) * L_ + lg];
            }
            int off = (row * 128 + cc2 * 4) ^ ((row & 7) << 4);
            *(unsigned*)((char*)xT + off) = pkbf(f0, f1);
        }
    }

    const int cl = lane & 31;
    const int hi = lane >> 5;

    // conv2 A-frags + conv1 bias (coalesced / tiny L2 loads, overlap staging)
    short8 a2[2];
    a2[0] = *(const short8*)(wf2 + ((b * 2 + 0) * 64 + lane) * 8);
    a2[1] = *(const short8*)(wf2 + ((b * 2 + 1) * 64 + lane) * 8);
    float bias1[16];
    #pragma unroll
    for (int r = 0; r < 16; ++r)
        bias1[r] = c1b[(r & 3) + 8 * (r >> 2) + 4 * hi];

    __syncthreads();

    // ---- conv1: 12 x mfma_32x32x16_bf16, A streamed from aF ----
    const int cb = wv * 32;
    float16 acc = (float16)0.0f;
    #pragma unroll
    for (int t = 0; t < 3; ++t) {
        int row = cb + cl + t;
        int rb  = row * 128;
        int swz = (row & 7) << 4;
        #pragma unroll
        for (int q = 0; q < 4; ++q) {
            short8 af = *(const short8*)(aF + ((t * 4 + q) * 64 + lane) * 8);
            int off = (rb + q * 32 + hi * 16) ^ swz;
            short8 bf = *(const short8*)((const char*)xT + off);
            acc = __builtin_amdgcn_mfma_f32_32x32x16_bf16(af, bf, acc, 0, 0, 0);
        }
    }

    // ---- bias + tanh ----
    float th[16];
    #pragma unroll
    for (int r = 0; r < 16; ++r)
        th[r] = tanhf(acc[r] + bias1[r]);

    // ---- conv2 B-frags in-register via half-wave swap (lane ^ 32) ----
    // C row of acc idx r (this lane) = (r&3) + 8*(r>>2) + 4*hi.
    // B-frag needs H[k = ks*16 + hi*8 + i][col=cl], i=0..7.
    unsigned x0a = hi ? pkbf(th[0],  th[1])  : pkbf(th[4],  th[5]);
    unsigned x0b = hi ? pkbf(th[2],  th[3])  : pkbf(th[6],  th[7]);
    unsigned x1a = hi ? pkbf(th[8],  th[9])  : pkbf(th[12], th[13]);
    unsigned x1b = hi ? pkbf(th[10], th[11]) : pkbf(th[14], th[15]);
    unsigned r0a = (unsigned)__shfl_xor((int)x0a, 32, 64);
    unsigned r0b = (unsigned)__shfl_xor((int)x0b, 32, 64);
    unsigned r1a = (unsigned)__shfl_xor((int)x1a, 32, 64);
    unsigned r1b = (unsigned)__shfl_xor((int)x1b, 32, 64);

    union U { short8 s8; unsigned u[4]; };
    U b0, b1;
    b0.u[0] = hi ? r0a : pkbf(th[0], th[1]);
    b0.u[1] = hi ? r0b : pkbf(th[2], th[3]);
    b0.u[2] = hi ? pkbf(th[4], th[5]) : r0a;
    b0.u[3] = hi ? pkbf(th[6], th[7]) : r0b;
    b1.u[0] = hi ? r1a : pkbf(th[8], th[9]);
    b1.u[1] = hi ? r1b : pkbf(th[10], th[11]);
    b1.u[2] = hi ? pkbf(th[12], th[13]) : r1a;
    b1.u[3] = hi ? pkbf(th[14], th[15]) : r1b;

    float16 acc2 = (float16)0.0f;
    acc2 = __builtin_amdgcn_mfma_f32_32x32x16_bf16(a2[0], b0.s8, acc2, 0, 0, 0);
    acc2 = __builtin_amdgcn_mfma_f32_32x32x16_bf16(a2[1], b1.s8, acc2, 0, 0, 0);

    // ---- bounce result through LDS (reuse smem), contiguous stores ----
    __syncthreads();  // all xT reads complete before overwrite
    #pragma unroll
    for (int r = 0; r < 16; ++r) {
        int row = (r & 3) + 8 * (r >> 2) + 4 * hi;
        smem[row * 136 + cb + cl] = acc2[r];
    }
    __syncthreads();

    const float* be = beff + b * OC_;
    float* ob_base = out + (size_t)b * (OC_ * (size_t)LP_);
    #pragma unroll
    for (int rep = 0; rep < 4; ++rep) {
        int row = (tid >> 5) + 8 * rep;
        int j   = (tid & 31) * 4;
        float4 v = *(const float4*)(smem + row * 136 + j);
        float bb = be[row];
        int gl = l0 + j;
        float* ob = ob_base + (size_t)row * LP_ + gl;
        if (gl + 3 < LP_) {
            float4 w = {v.x + bb, v.y + bb, v.z + bb, v.w + bb};
            *(float4*)ob = w;
        } else {
            float vv[4] = {v.x, v.y, v.z, v.w};
            #pragma unroll
            for (int e = 0; e < 4; ++e)
                if (gl + e < LP_) ob[e] = vv[e] + bb;
        }
    }
}

// ---------------------------------------------------------------------------
extern "C" void kernel_launch(void* const* d_in, const int* in_sizes, int n_in,
                              void* d_out, int out_size, void* d_ws, size_t ws_size,
                              hipStream_t stream)
{
    const float* x      = (const float*)d_in[0];
    const float* w_gate = (const float*)d_in[1];
    const float* c1w    = (const float*)d_in[2];
    const float* c1b    = (const float*)d_in[3];
    const float* c2w    = (const float*)d_in[4];
    const float* c2b    = (const float*)d_in[5];
    float* out = (float*)d_out;

    char* ws = (char*)d_ws;
    float* beff         = (float*)ws;                    // 4096 B
    unsigned short* aF  = (unsigned short*)(ws + 4096);  // 12288 B
    unsigned short* wf2 = (unsigned short*)(ws + 16384); // 65536 B

    prep_kernel<<<9, 256, 0, stream>>>(x, w_gate, c1w, c2w, c2b, beff, aF, wf2);
    fused_main<<<B_ * NT, 256, 0, stream>>>(x, aF, wf2, beff, c1b, out);
}

// Round 5
// 23.026 us; speedup vs baseline: 2.4055x; 1.1043x over previous
//
#include <hip/hip_runtime.h>
#include <math.h>

// Problem constants
#define B_  32
#define D_  64
#define L_  4096
#define E_  8
#define OC_ 32
#define LP_ 4094   // L - 2 (VALID conv, kernel 3)
#define TILE 128
#define NT   32    // tiles per batch (4096/128)

typedef __attribute__((ext_vector_type(8)))  short short8;
typedef __attribute__((ext_vector_type(16))) float float16;

static __device__ __forceinline__ unsigned short f2bf(float f) {
    unsigned u = __float_as_uint(f);
    return (unsigned short)((u + 0x7fffu + ((u >> 16) & 1u)) >> 16);
}
// packed f32x2 -> bf16x2 (low = a, high = b) in ONE instruction
static __device__ __forceinline__ unsigned cvtpk(float a, float b) {
    unsigned r;
    asm("v_cvt_pk_bf16_f32 %0, %1, %2" : "=v"(r) : "v"(a), "v"(b));
    return r;
}
// tanh via hw exp + rcp: 1 - 2/(e^{2x}+1)   (~5 VALU ops, err ~1e-5)
static __device__ __forceinline__ float fast_tanh(float x) {
    float e = __expf(2.0f * x);
    return fmaf(-2.0f, __builtin_amdgcn_rcpf(e + 1.0f), 1.0f);
}

// ---------------------------------------------------------------------------
// Workspace: beff f32[32][32] @0 (4KB) | aF bf16[12][64][8] @4096 (12KB)
//            wf2 bf16[B][2][64][8] @16384 (64KB)
// ---------------------------------------------------------------------------

// Prep: blocks 0..7 (wave w -> batch 4*blk+w): gates + Weff frags + beff.
//       block 8: conv1 A-fragments.
__global__ __launch_bounds__(256)
void prep_kernel(const float* __restrict__ x,
                 const float* __restrict__ w_gate,
                 const float* __restrict__ c1w,
                 const float* __restrict__ c2w,
                 const float* __restrict__ c2b,
                 float* __restrict__ beff,
                 unsigned short* __restrict__ aF,
                 unsigned short* __restrict__ wf2)
{
    const int tid = threadIdx.x;

    if (blockIdx.x == 8) {
        for (int i = tid; i < 12 * 64 * 8; i += 256) {
            int ks = i >> 9, lane = (i >> 3) & 63, ii = i & 7;
            int oc = lane & 31, half = lane >> 5;
            int kp = ks * 16 + half * 8 + ii;
            int t = kp >> 6, c = kp & 63;
            aF[i] = f2bf(c1w[oc * 192 + c * 3 + t]);
        }
        return;
    }

    const int wv = tid >> 6, lane = tid & 63;
    const int b  = blockIdx.x * 4 + wv;
    const int d  = lane;

    float xv[5];
    #pragma unroll
    for (int t = 0; t < 5; ++t)
        xv[t] = x[((size_t)b * D_ + d) * L_ + (L_ - 6) + t];

    float part[E_];
    #pragma unroll
    for (int e = 0; e < E_; ++e) part[e] = 0.f;
    #pragma unroll
    for (int t = 0; t < 5; ++t) {
        const float* wg = w_gate + (d * 5 + t) * E_;
        #pragma unroll
        for (int e = 0; e < E_; ++e) part[e] += xv[t] * wg[e];
    }
    #pragma unroll
    for (int off = 1; off < 64; off <<= 1) {
        #pragma unroll
        for (int e = 0; e < E_; ++e)
            part[e] += __shfl_xor(part[e], off, 64);
    }
    float m = part[0];
    #pragma unroll
    for (int e = 1; e < E_; ++e) m = fmaxf(m, part[e]);
    float p[E_], s = 0.f;
    #pragma unroll
    for (int e = 0; e < E_; ++e) { p[e] = expf(part[e] - m); s += p[e]; }
    float inv = 1.f / s;
    #pragma unroll
    for (int e = 0; e < E_; ++e) p[e] *= inv;

    int i0 = 0;
    #pragma unroll
    for (int e = 1; e < E_; ++e) if (p[e] > p[i0]) i0 = e;
    int i1 = (i0 == 0) ? 1 : 0;
    #pragma unroll
    for (int e = 0; e < E_; ++e) {
        if (e == i0) continue;
        if (p[e] > p[i1]) i1 = e;
    }
    const float v0 = p[i0], v1 = p[i1];
    const float den = v0 + v1 + 1e-6f;
    const float g0 = v0 / den, g1 = v1 / den;

    // Weff A-frags: A[m=dd=cl][k=oc], oc = ks*16 + (lane>>5)*8 + i
    {
        const int dd = lane & 31, half = lane >> 5;
        #pragma unroll
        for (int ks = 0; ks < 2; ++ks) {
            #pragma unroll
            for (int i = 0; i < 8; ++i) {
                int oc = ks * 16 + half * 8 + i;
                float v = g0 * c2w[(dd * E_ + i0) * OC_ + oc]
                        + g1 * c2w[(dd * E_ + i1) * OC_ + oc];
                wf2[((b * 2 + ks) * 64 + lane) * 8 + i] = f2bf(v);
            }
        }
    }
    if (d < OC_)
        beff[b * OC_ + d] = g0 * c2b[d * E_ + i0] + g1 * c2b[d * E_ + i1];
}

// ---------------------------------------------------------------------------
// Fused main. Block = (batch, 128-col tile); 4 waves, one 32-col MFMA tile
// each. ONE barrier; conv2 B-operand via half-wave shuffle swap; direct
// MFMA-layout stores (proven exact WRITE_SIZE in R1/R2).
// ---------------------------------------------------------------------------
__global__ __launch_bounds__(256, 6)
void fused_main(const float* __restrict__ x,
                const unsigned short* __restrict__ aF,   // [12][64][8]
                const unsigned short* __restrict__ wf2,  // [B][2][64][8]
                const float* __restrict__ beff,          // [B][32]
                const float* __restrict__ c1b,           // [32]
                float* __restrict__ out)                 // [B][32][4094]
{
    // xT: bf16 [130 rows(l)][64 c] pitch 128 B, XOR-swizzle (row&7)<<4
    __shared__ __align__(16) unsigned short xT[130 * 64];

    const int tid  = threadIdx.x;
    const int lane = tid & 63;
    const int wv   = tid >> 6;
    const int b    = blockIdx.x >> 5;
    const int l0   = (blockIdx.x & 31) << 7;
    const float* xb = x + (size_t)b * (D_ * L_);

    // ---- stage x tile: f32 [c][l] -> bf16 xT[l][c] (c-pairs packed) ----
    {
        const int c2 = tid >> 3;          // 0..31 channel pair
        const int jb = (tid & 7) << 2;
        const float* p0 = xb + (size_t)(2 * c2) * L_ + l0;
        const float* p1 = p0 + L_;
        #pragma unroll
        for (int jq = 0; jq < 4; ++jq) {
            int j = jq * 32 + jb;
            float4 v0 = *(const float4*)(p0 + j);
            float4 v1 = *(const float4*)(p1 + j);
            float e0[4] = {v0.x, v0.y, v0.z, v0.w};
            float e1[4] = {v1.x, v1.y, v1.z, v1.w};
            #pragma unroll
            for (int r = 0; r < 4; ++r) {
                int row = j + r;
                int off = (row * 128 + c2 * 4) ^ ((row & 7) << 4);
                *(unsigned*)((char*)xT + off) = cvtpk(e0[r], e1[r]);
            }
        }
        if (tid < 64) {  // halo rows 128,129
            int cc2 = tid >> 1, jj = tid & 1;
            int row = TILE + jj;
            int lg  = l0 + row;
            float f0 = 0.f, f1 = 0.f;
            if (lg < L_) {
                f0 = xb[(size_t)(2 * cc2) * L_ + lg];
                f1 = xb[(size_t)(2 * cc2 + 1) * L_ + lg];
            }
            int off = (row * 128 + cc2 * 4) ^ ((row & 7) << 4);
            *(unsigned*)((char*)xT + off) = cvtpk(f0, f1);
        }
    }

    const int cl = lane & 31;
    const int hi = lane >> 5;

    // conv2 A-frags + conv1 bias (tiny L2 loads, overlap staging latency)
    short8 a2[2];
    a2[0] = *(const short8*)(wf2 + ((b * 2 + 0) * 64 + lane) * 8);
    a2[1] = *(const short8*)(wf2 + ((b * 2 + 1) * 64 + lane) * 8);
    float bias1[16];
    #pragma unroll
    for (int r = 0; r < 16; ++r)
        bias1[r] = c1b[(r & 3) + 8 * (r >> 2) + 4 * hi];

    __syncthreads();

    // ---- conv1: 12 x mfma_32x32x16_bf16, A streamed from aF ----
    const int cb = wv * 32;
    float16 acc = (float16)0.0f;
    #pragma unroll
    for (int t = 0; t < 3; ++t) {
        int row = cb + cl + t;
        int rb  = row * 128;
        int swz = (row & 7) << 4;
        #pragma unroll
        for (int q = 0; q < 4; ++q) {
            short8 af = *(const short8*)(aF + ((t * 4 + q) * 64 + lane) * 8);
            int off = (rb + q * 32 + hi * 16) ^ swz;
            short8 bf = *(const short8*)((const char*)xT + off);
            acc = __builtin_amdgcn_mfma_f32_32x32x16_bf16(af, bf, acc, 0, 0, 0);
        }
    }

    // ---- bias + fast tanh ----
    float th[16];
    #pragma unroll
    for (int r = 0; r < 16; ++r)
        th[r] = fast_tanh(acc[r] + bias1[r]);

    // ---- conv2 B-frags in-register via half-wave swap (lane ^ 32) ----
    unsigned x0a = hi ? cvtpk(th[0],  th[1])  : cvtpk(th[4],  th[5]);
    unsigned x0b = hi ? cvtpk(th[2],  th[3])  : cvtpk(th[6],  th[7]);
    unsigned x1a = hi ? cvtpk(th[8],  th[9])  : cvtpk(th[12], th[13]);
    unsigned x1b = hi ? cvtpk(th[10], th[11]) : cvtpk(th[14], th[15]);
    unsigned r0a = (unsigned)__shfl_xor((int)x0a, 32, 64);
    unsigned r0b = (unsigned)__shfl_xor((int)x0b, 32, 64);
    unsigned r1a = (unsigned)__shfl_xor((int)x1a, 32, 64);
    unsigned r1b = (unsigned)__shfl_xor((int)x1b, 32, 64);

    union U { short8 s8; unsigned u[4]; };
    U b0, b1;
    b0.u[0] = hi ? r0a : cvtpk(th[0], th[1]);
    b0.u[1] = hi ? r0b : cvtpk(th[2], th[3]);
    b0.u[2] = hi ? cvtpk(th[4], th[5]) : r0a;
    b0.u[3] = hi ? cvtpk(th[6], th[7]) : r0b;
    b1.u[0] = hi ? r1a : cvtpk(th[8], th[9]);
    b1.u[1] = hi ? r1b : cvtpk(th[10], th[11]);
    b1.u[2] = hi ? cvtpk(th[12], th[13]) : r1a;
    b1.u[3] = hi ? cvtpk(th[14], th[15]) : r1b;

    float16 acc2 = (float16)0.0f;
    acc2 = __builtin_amdgcn_mfma_f32_32x32x16_bf16(a2[0], b0.s8, acc2, 0, 0, 0);
    acc2 = __builtin_amdgcn_mfma_f32_32x32x16_bf16(a2[1], b1.s8, acc2, 0, 0, 0);

    // ---- direct stores (128B-chunk per half-wave; exact WRITE_SIZE) ----
    int l = l0 + cb + cl;
    if (l < LP_) {
        const float* be = beff + b * OC_;
        float* ob = out + (size_t)b * (OC_ * (size_t)LP_) + l;
        #pragma unroll
        for (int r = 0; r < 16; ++r) {
            int row = (r & 3) + 8 * (r >> 2) + 4 * hi;
            ob[(size_t)row * LP_] = acc2[r] + be[row];
        }
    }
}

// ---------------------------------------------------------------------------
extern "C" void kernel_launch(void* const* d_in, const int* in_sizes, int n_in,
                              void* d_out, int out_size, void* d_ws, size_t ws_size,
                              hipStream_t stream)
{
    const float* x      = (const float*)d_in[0];
    const float* w_gate = (const float*)d_in[1];
    const float* c1w    = (const float*)d_in[2];
    const float* c1b    = (const float*)d_in[3];
    const float* c2w    = (const float*)d_in[4];
    const float* c2b    = (const float*)d_in[5];
    float* out = (float*)d_out;

    char* ws = (char*)d_ws;
    float* beff         = (float*)ws;                    // 4096 B
    unsigned short* aF  = (unsigned short*)(ws + 4096);  // 12288 B
    unsigned short* wf2 = (unsigned short*)(ws + 16384); // 65536 B

    prep_kernel<<<9, 256, 0, stream>>>(x, w_gate, c1w, c2w, c2b, beff, aF, wf2);
    fused_main<<<B_ * NT, 256, 0, stream>>>(x, aF, wf2, beff, c1b, out);
}

// Round 6
// 22.004 us; speedup vs baseline: 2.5172x; 1.0464x over previous
//
#include <hip/hip_runtime.h>
#include <math.h>

// Problem constants
#define B_  32
#define D_  64
#define L_  4096
#define E_  8
#define OC_ 32
#define LP_ 4094   // L - 2 (VALID conv, kernel 3)
#define TILE 128
#define NT   32    // tiles per batch (4096/128)

typedef __attribute__((ext_vector_type(8)))  short short8;
typedef __attribute__((ext_vector_type(16))) float float16;

static __device__ __forceinline__ unsigned short f2bf(float f) {
    unsigned u = __float_as_uint(f);
    return (unsigned short)((u + 0x7fffu + ((u >> 16) & 1u)) >> 16);
}
// packed f32x2 -> bf16x2 (low = a, high = b) in ONE instruction
static __device__ __forceinline__ unsigned cvtpk(float a, float b) {
    unsigned r;
    asm("v_cvt_pk_bf16_f32 %0, %1, %2" : "=v"(r) : "v"(a), "v"(b));
    return r;
}
// tanh via hw exp + rcp: 1 - 2/(e^{2x}+1)   (~5 VALU ops, err ~1e-5)
static __device__ __forceinline__ float fast_tanh(float x) {
    float e = __expf(2.0f * x);
    return fmaf(-2.0f, __builtin_amdgcn_rcpf(e + 1.0f), 1.0f);
}

// ---------------------------------------------------------------------------
// Workspace: beff f32[32][32] @0 (4KB) | aF bf16[12][64][8] @4096 (12KB)
//            wf2 bf16[B][2][64][8] @16384 (64KB)
// ---------------------------------------------------------------------------

// Prep: blocks 0..7 (wave w -> batch 4*blk+w): gates + Weff frags + beff.
//       block 8: conv1 A-fragments.
__global__ __launch_bounds__(256)
void prep_kernel(const float* __restrict__ x,
                 const float* __restrict__ w_gate,
                 const float* __restrict__ c1w,
                 const float* __restrict__ c2w,
                 const float* __restrict__ c2b,
                 float* __restrict__ beff,
                 unsigned short* __restrict__ aF,
                 unsigned short* __restrict__ wf2)
{
    const int tid = threadIdx.x;

    if (blockIdx.x == 8) {
        for (int i = tid; i < 12 * 64 * 8; i += 256) {
            int ks = i >> 9, lane = (i >> 3) & 63, ii = i & 7;
            int oc = lane & 31, half = lane >> 5;
            int kp = ks * 16 + half * 8 + ii;
            int t = kp >> 6, c = kp & 63;
            aF[i] = f2bf(c1w[oc * 192 + c * 3 + t]);
        }
        return;
    }

    const int wv = tid >> 6, lane = tid & 63;
    const int b  = blockIdx.x * 4 + wv;
    const int d  = lane;

    float xv[5];
    #pragma unroll
    for (int t = 0; t < 5; ++t)
        xv[t] = x[((size_t)b * D_ + d) * L_ + (L_ - 6) + t];

    float part[E_];
    #pragma unroll
    for (int e = 0; e < E_; ++e) part[e] = 0.f;
    #pragma unroll
    for (int t = 0; t < 5; ++t) {
        const float* wg = w_gate + (d * 5 + t) * E_;
        #pragma unroll
        for (int e = 0; e < E_; ++e) part[e] += xv[t] * wg[e];
    }
    #pragma unroll
    for (int off = 1; off < 64; off <<= 1) {
        #pragma unroll
        for (int e = 0; e < E_; ++e)
            part[e] += __shfl_xor(part[e], off, 64);
    }
    float m = part[0];
    #pragma unroll
    for (int e = 1; e < E_; ++e) m = fmaxf(m, part[e]);
    float p[E_], s = 0.f;
    #pragma unroll
    for (int e = 0; e < E_; ++e) { p[e] = expf(part[e] - m); s += p[e]; }
    float inv = 1.f / s;
    #pragma unroll
    for (int e = 0; e < E_; ++e) p[e] *= inv;

    int i0 = 0;
    #pragma unroll
    for (int e = 1; e < E_; ++e) if (p[e] > p[i0]) i0 = e;
    int i1 = (i0 == 0) ? 1 : 0;
    #pragma unroll
    for (int e = 0; e < E_; ++e) {
        if (e == i0) continue;
        if (p[e] > p[i1]) i1 = e;
    }
    const float v0 = p[i0], v1 = p[i1];
    const float den = v0 + v1 + 1e-6f;
    const float g0 = v0 / den, g1 = v1 / den;

    // Weff A-frags: A[m=dd=cl][k=oc], oc = ks*16 + (lane>>5)*8 + i
    {
        const int dd = lane & 31, half = lane >> 5;
        #pragma unroll
        for (int ks = 0; ks < 2; ++ks) {
            #pragma unroll
            for (int i = 0; i < 8; ++i) {
                int oc = ks * 16 + half * 8 + i;
                float v = g0 * c2w[(dd * E_ + i0) * OC_ + oc]
                        + g1 * c2w[(dd * E_ + i1) * OC_ + oc];
                wf2[((b * 2 + ks) * 64 + lane) * 8 + i] = f2bf(v);
            }
        }
    }
    if (d < OC_)
        beff[b * OC_ + d] = g0 * c2b[d * E_ + i0] + g1 * c2b[d * E_ + i1];
}

// ---------------------------------------------------------------------------
// Fused main. Block = (batch, 128-col tile); 4 waves, one 32-col MFMA tile
// each. ONE barrier; conv2 B-operand via half-wave shuffle swap; direct
// MFMA-layout stores. launch_bounds(256,4): VGPR<=128, NO spills (grid is
// 4 blocks/CU resident max anyway, so a tighter bound only causes scratch).
// ---------------------------------------------------------------------------
__global__ __launch_bounds__(256, 4)
void fused_main(const float* __restrict__ x,
                const unsigned short* __restrict__ aF,   // [12][64][8]
                const unsigned short* __restrict__ wf2,  // [B][2][64][8]
                const float* __restrict__ beff,          // [B][32]
                const float* __restrict__ c1b,           // [32]
                float* __restrict__ out)                 // [B][32][4094]
{
    // xT: bf16 [130 rows(l)][64 c] pitch 128 B, XOR-swizzle (row&7)<<4
    __shared__ __align__(16) unsigned short xT[130 * 64];

    const int tid  = threadIdx.x;
    const int lane = tid & 63;
    const int wv   = tid >> 6;
    const int b    = blockIdx.x >> 5;
    const int l0   = (blockIdx.x & 31) << 7;
    const float* xb = x + (size_t)b * (D_ * L_);

    // ---- stage x tile: f32 [c][l] -> bf16 xT[l][c] (c-pairs packed) ----
    {
        const int c2 = tid >> 3;          // 0..31 channel pair
        const int jb = (tid & 7) << 2;
        const float* p0 = xb + (size_t)(2 * c2) * L_ + l0;
        const float* p1 = p0 + L_;
        #pragma unroll
        for (int jq = 0; jq < 4; ++jq) {
            int j = jq * 32 + jb;
            float4 v0 = *(const float4*)(p0 + j);
            float4 v1 = *(const float4*)(p1 + j);
            float e0[4] = {v0.x, v0.y, v0.z, v0.w};
            float e1[4] = {v1.x, v1.y, v1.z, v1.w};
            #pragma unroll
            for (int r = 0; r < 4; ++r) {
                int row = j + r;
                int off = (row * 128 + c2 * 4) ^ ((row & 7) << 4);
                *(unsigned*)((char*)xT + off) = cvtpk(e0[r], e1[r]);
            }
        }
        if (tid < 64) {  // halo rows 128,129
            int cc2 = tid >> 1, jj = tid & 1;
            int row = TILE + jj;
            int lg  = l0 + row;
            float f0 = 0.f, f1 = 0.f;
            if (lg < L_) {
                f0 = xb[(size_t)(2 * cc2) * L_ + lg];
                f1 = xb[(size_t)(2 * cc2 + 1) * L_ + lg];
            }
            int off = (row * 128 + cc2 * 4) ^ ((row & 7) << 4);
            *(unsigned*)((char*)xT + off) = cvtpk(f0, f1);
        }
    }

    const int cl = lane & 31;
    const int hi = lane >> 5;

    __syncthreads();

    // ---- conv1: 12 x mfma_32x32x16_bf16, A streamed from aF ----
    const int cb = wv * 32;
    float16 acc = (float16)0.0f;
    #pragma unroll
    for (int t = 0; t < 3; ++t) {
        int row = cb + cl + t;
        int rb  = row * 128;
        int swz = (row & 7) << 4;
        #pragma unroll
        for (int q = 0; q < 4; ++q) {
            short8 af = *(const short8*)(aF + ((t * 4 + q) * 64 + lane) * 8);
            int off = (rb + q * 32 + hi * 16) ^ swz;
            short8 bf = *(const short8*)((const char*)xT + off);
            acc = __builtin_amdgcn_mfma_f32_32x32x16_bf16(af, bf, acc, 0, 0, 0);
        }
    }

    // conv2 A-frags (L2-hit loads; deferred to keep conv1-phase VGPR low)
    short8 a2[2];
    a2[0] = *(const short8*)(wf2 + ((b * 2 + 0) * 64 + lane) * 8);
    a2[1] = *(const short8*)(wf2 + ((b * 2 + 1) * 64 + lane) * 8);

    // ---- bias + fast tanh ----
    float th[16];
    #pragma unroll
    for (int r = 0; r < 16; ++r) {
        int row = (r & 3) + 8 * (r >> 2) + 4 * hi;
        th[r] = fast_tanh(acc[r] + c1b[row]);
    }

    // ---- conv2 B-frags in-register via half-wave swap (lane ^ 32) ----
    unsigned x0a = hi ? cvtpk(th[0],  th[1])  : cvtpk(th[4],  th[5]);
    unsigned x0b = hi ? cvtpk(th[2],  th[3])  : cvtpk(th[6],  th[7]);
    unsigned x1a = hi ? cvtpk(th[8],  th[9])  : cvtpk(th[12], th[13]);
    unsigned x1b = hi ? cvtpk(th[10], th[11]) : cvtpk(th[14], th[15]);
    unsigned r0a = (unsigned)__shfl_xor((int)x0a, 32, 64);
    unsigned r0b = (unsigned)__shfl_xor((int)x0b, 32, 64);
    unsigned r1a = (unsigned)__shfl_xor((int)x1a, 32, 64);
    unsigned r1b = (unsigned)__shfl_xor((int)x1b, 32, 64);

    union U { short8 s8; unsigned u[4]; };
    U b0, b1;
    b0.u[0] = hi ? r0a : cvtpk(th[0], th[1]);
    b0.u[1] = hi ? r0b : cvtpk(th[2], th[3]);
    b0.u[2] = hi ? cvtpk(th[4], th[5]) : r0a;
    b0.u[3] = hi ? cvtpk(th[6], th[7]) : r0b;
    b1.u[0] = hi ? r1a : cvtpk(th[8], th[9]);
    b1.u[1] = hi ? r1b : cvtpk(th[10], th[11]);
    b1.u[2] = hi ? cvtpk(th[12], th[13]) : r1a;
    b1.u[3] = hi ? cvtpk(th[14], th[15]) : r1b;

    float16 acc2 = (float16)0.0f;
    acc2 = __builtin_amdgcn_mfma_f32_32x32x16_bf16(a2[0], b0.s8, acc2, 0, 0, 0);
    acc2 = __builtin_amdgcn_mfma_f32_32x32x16_bf16(a2[1], b1.s8, acc2, 0, 0, 0);

    // ---- direct stores (128B chunk per half-wave row) ----
    int l = l0 + cb + cl;
    if (l < LP_) {
        const float* be = beff + b * OC_;
        float* ob = out + (size_t)b * (OC_ * (size_t)LP_) + l;
        #pragma unroll
        for (int r = 0; r < 16; ++r) {
            int row = (r & 3) + 8 * (r >> 2) + 4 * hi;
            ob[(size_t)row * LP_] = acc2[r] + be[row];
        }
    }
}

// ---------------------------------------------------------------------------
extern "C" void kernel_launch(void* const* d_in, const int* in_sizes, int n_in,
                              void* d_out, int out_size, void* d_ws, size_t ws_size,
                              hipStream_t stream)
{
    const float* x      = (const float*)d_in[0];
    const float* w_gate = (const float*)d_in[1];
    const float* c1w    = (const float*)d_in[2];
    const float* c1b    = (const float*)d_in[3];
    const float* c2w    = (const float*)d_in[4];
    const float* c2b    = (const float*)d_in[5];
    float* out = (float*)d_out;

    char* ws = (char*)d_ws;
    float* beff         = (float*)ws;                    // 4096 B
    unsigned short* aF  = (unsigned short*)(ws + 4096);  // 12288 B
    unsigned short* wf2 = (unsigned short*)(ws + 16384); // 65536 B

    prep_kernel<<<9, 256, 0, stream>>>(x, w_gate, c1w, c2w, c2b, beff, aF, wf2);
    fused_main<<<B_ * NT, 256, 0, stream>>>(x, aF, wf2, beff, c1b, out);
}